// Round 12
// baseline (75.980 us; speedup 1.0000x reference)
//
#include <hip/hip_runtime.h>
#include <hip/hip_bf16.h>

typedef __attribute__((ext_vector_type(8))) short short8;
typedef __attribute__((ext_vector_type(4))) float f32x4;
typedef __attribute__((ext_vector_type(4))) unsigned int u32x4;
typedef __attribute__((ext_vector_type(2))) unsigned int u32x2;

#define DFEAT 128
#define LDW 136    // W^T row stride (shorts)
#define LDZ 136    // z-tile row stride (shorts): 272B rows -> <=2-way banks on b128

__device__ __forceinline__ unsigned short f2bf(float f) {
    unsigned int u = __float_as_uint(f);
    u += 0x7FFFu + ((u >> 16) & 1u);   // round-nearest-even
    return (unsigned short)(u >> 16);
}
// packed f32x2 -> bf16x2, RNE (gfx950 v_cvt_pk_bf16_f32)
__device__ __forceinline__ unsigned int cvt2(float lo, float hi) {
    unsigned int r;
    asm("v_cvt_pk_bf16_f32 %0, %1, %2" : "=v"(r) : "v"(lo), "v"(hi));
    return r;
}
__device__ __forceinline__ float bf2f(unsigned int bits) {
    return __uint_as_float(bits << 16);
}

// node_gemm v7: cooperative strips (round-11 structure) + 2-deep transit
// pipeline. Block owns each 16x128 strip; wave w owns cols [w*32,w*32+32)
// with its 8 W^T fragments hoisted to VGPRs once. z staged through a bf16
// LDS double buffer; per thread 32B via 2 asm-pinned dwordx4.
// KEY CHANGE vs round 11: loads for strip s+2G are issued at iter top and
// waited one FULL iteration later (gap >> HBM latency), using two named
// transit pairs A/B. In-order VMEM accounting (2 loads + 2 stores /thread
// /iter): prologue vmcnt(2); peeled iter0 vmcnt(4); steady vmcnt(6).
// Loads always issued (clamped addr) -> uniform counts; store count uniform
// because launcher guards nN % 16 == 0.
__global__ __launch_bounds__(256) void node_gemm(
    const float* __restrict__ zi, const float* __restrict__ zj,
    const float* __restrict__ W1, const float* __restrict__ b1,
    unsigned short* __restrict__ Aout, unsigned short* __restrict__ Bout,
    int nN)
{
    union SMem {
        unsigned short wt[128][LDW];     // 34816 B, W^T staging (prologue only)
        unsigned short zb[2][16][LDZ];   //  8704 B, z double buffer
    };
    __shared__ SMem sm;

    const int table = blockIdx.y;
    const float* __restrict__ z = table ? zj : zi;
    unsigned short* __restrict__ outp = table ? Bout : Aout;
    const int tid = threadIdx.x;

    for (int idx = tid; idx < 128 * 128; idx += 256) {
        int c = idx & 127, k = idx >> 7;
        sm.wt[c][k] = f2bf(W1[(size_t)(table * 128 + k) * DFEAT + c]);
    }
    __syncthreads();

    const int lane = tid & 63;
    const int l15  = lane & 15;
    const int kg   = lane >> 4;
    const int w    = tid >> 6;
    const int cbase = w * 32;

    short8 wf[2][4];
#pragma unroll
    for (int ci = 0; ci < 2; ++ci)
#pragma unroll
        for (int kk = 0; kk < 4; ++kk)
            wf[ci][kk] = *(const short8*)&sm.wt[cbase + ci * 16 + l15][kk * 32 + kg * 8];

    f32x4 biasv[2];
    if (table == 0) {
#pragma unroll
        for (int ci = 0; ci < 2; ++ci)
            biasv[ci] = *(const f32x4*)&b1[cbase + ci * 16 + kg * 4];
    } else {
        biasv[0] = (f32x4){0.f, 0.f, 0.f, 0.f};
        biasv[1] = (f32x4){0.f, 0.f, 0.f, 0.f};
    }
    __syncthreads();   // wt reads done; zb may overwrite

    const int nStrips = (nN + 15) >> 4;
    const int G = gridDim.x;
    const int r    = tid >> 4;           // staging row 0..15
    const int coff = (tid & 15) * 8;     // staging col (floats)

    auto gaddr = [&](int s) {
        int row = s * 16 + r;
        if (row >= nN) row = nN - 1;     // clamp: issued loads always legal
        return z + (size_t)row * DFEAT + coff;
    };

    f32x4 t0A, t1A, t0B, t1B;
    auto issueA = [&](int s) {
        const float* gp = gaddr(s);
        asm volatile("global_load_dwordx4 %0, %1, off"           : "=&v"(t0A) : "v"(gp) : "memory");
        asm volatile("global_load_dwordx4 %0, %1, off offset:16" : "=&v"(t1A) : "v"(gp) : "memory");
    };
    auto issueB = [&](int s) {
        const float* gp = gaddr(s);
        asm volatile("global_load_dwordx4 %0, %1, off"           : "=&v"(t0B) : "v"(gp) : "memory");
        asm volatile("global_load_dwordx4 %0, %1, off offset:16" : "=&v"(t1B) : "v"(gp) : "memory");
    };
    auto writeA = [&](int buf) {
        u32x4 v;
        v[0] = cvt2(t0A[0], t0A[1]); v[1] = cvt2(t0A[2], t0A[3]);
        v[2] = cvt2(t1A[0], t1A[1]); v[3] = cvt2(t1A[2], t1A[3]);
        *(u32x4*)&sm.zb[buf][r][coff] = v;
    };
    auto writeB = [&](int buf) {
        u32x4 v;
        v[0] = cvt2(t0B[0], t0B[1]); v[1] = cvt2(t0B[2], t0B[3]);
        v[2] = cvt2(t1B[0], t1B[1]); v[3] = cvt2(t1B[2], t1B[3]);
        *(u32x4*)&sm.zb[buf][r][coff] = v;
    };
    auto compute = [&](int s, int buf) {
        f32x4 acc0 = biasv[0], acc1 = biasv[1];
#pragma unroll
        for (int kk = 0; kk < 4; ++kk) {
            short8 zf = *(const short8*)&sm.zb[buf][l15][kk * 32 + kg * 8];
            acc0 = __builtin_amdgcn_mfma_f32_16x16x32_bf16(wf[0][kk], zf, acc0, 0, 0, 0);
            acc1 = __builtin_amdgcn_mfma_f32_16x16x32_bf16(wf[1][kk], zf, acc1, 0, 0, 0);
        }
        int row = s * 16 + l15;
        if (row < nN) {
            unsigned short* op = outp + (size_t)row * DFEAT + cbase + kg * 4;
            u32x2 v0; v0[0] = cvt2(acc0[0], acc0[1]); v0[1] = cvt2(acc0[2], acc0[3]);
            *(u32x2*)op = v0;
            u32x2 v1; v1[0] = cvt2(acc1[0], acc1[1]); v1[1] = cvt2(acc1[2], acc1[3]);
            *(u32x2*)(op + 16) = v1;
        }
    };

    int s = blockIdx.x;
    // prologue: A <- strip s, B <- strip s+G
    issueA(s);
    issueB(s + G);
    asm volatile("s_waitcnt vmcnt(2)" ::: "memory");   // retire A (B stays)
    __builtin_amdgcn_sched_barrier(0);
    writeA(0);
    __syncthreads();

    if (s < nStrips) {
        // peeled iter0: compute s (buf0); A free -> issue s+2G
        issueA(s + 2 * G);
        compute(s, 0);
        // queue after B: A(2) + stores(2) = 4
        asm volatile("s_waitcnt vmcnt(4)" ::: "memory");
        __builtin_amdgcn_sched_barrier(0);
        writeB(1);
        __syncthreads();

        int sc = s + G;
        while (sc < nStrips) {
            // odd iter: compute sc (buf1); B free -> issue sc+2G; wait A
            issueB(sc + 2 * G);
            compute(sc, 1);
            asm volatile("s_waitcnt vmcnt(6)" ::: "memory");
            __builtin_amdgcn_sched_barrier(0);
            writeA(0);
            __syncthreads();
            sc += G;
            if (sc >= nStrips) break;
            // even iter: compute sc (buf0); A free -> issue sc+2G; wait B
            issueA(sc + 2 * G);
            compute(sc, 0);
            asm volatile("s_waitcnt vmcnt(6)" ::: "memory");
            __builtin_amdgcn_sched_barrier(0);
            writeB(1);
            __syncthreads();
            sc += G;
        }
    }
}

// Phase 2: 16 lanes/edge, FOUR quads unrolled = 16 edges/wave/iter,
// 8 independent 16B gathers in flight (round-6 pattern, deeper).
__global__ __launch_bounds__(256) void edge_kernel(
    const unsigned short* __restrict__ A, const unsigned short* __restrict__ B,
    const int* __restrict__ src, const int* __restrict__ dst,
    const float* __restrict__ W3, const float* __restrict__ b3,
    float* __restrict__ out, int nE)
{
    const int lane = threadIdx.x & 63;
    const int sub  = lane & 15;
    const int grp  = lane >> 4;

    float w3v[8];
#pragma unroll
    for (int j = 0; j < 8; ++j) w3v[j] = W3[sub * 8 + j];
    const float bb = b3[0];

    int wv = blockIdx.x * 4 + (threadIdx.x >> 6);
    int nw = gridDim.x * 4;

    for (int base = wv * 16; base < nE; base += nw * 16) {
        int e0 = base + grp;
        int e1 = base + 4 + grp;
        int e2 = base + 8 + grp;
        int e3 = base + 12 + grp;
        bool v0 = e0 < nE, v1 = e1 < nE, v2 = e2 < nE, v3 = e3 < nE;
        int s0 = v0 ? src[e0] : 0, d0 = v0 ? dst[e0] : 0;
        int s1 = v1 ? src[e1] : 0, d1 = v1 ? dst[e1] : 0;
        int s2 = v2 ? src[e2] : 0, d2 = v2 ? dst[e2] : 0;
        int s3 = v3 ? src[e3] : 0, d3 = v3 ? dst[e3] : 0;

        u32x4 av0 = *(const u32x4*)(A + (size_t)s0 * DFEAT + sub * 8);
        u32x4 bv0 = *(const u32x4*)(B + (size_t)d0 * DFEAT + sub * 8);
        u32x4 av1 = *(const u32x4*)(A + (size_t)s1 * DFEAT + sub * 8);
        u32x4 bv1 = *(const u32x4*)(B + (size_t)d1 * DFEAT + sub * 8);
        u32x4 av2 = *(const u32x4*)(A + (size_t)s2 * DFEAT + sub * 8);
        u32x4 bv2 = *(const u32x4*)(B + (size_t)d2 * DFEAT + sub * 8);
        u32x4 av3 = *(const u32x4*)(A + (size_t)s3 * DFEAT + sub * 8);
        u32x4 bv3 = *(const u32x4*)(B + (size_t)d3 * DFEAT + sub * 8);

        float p0 = 0.f, p1 = 0.f, p2 = 0.f, p3 = 0.f;
#pragma unroll
        for (int w = 0; w < 4; ++w) {
            float wa = w3v[w * 2], wbv = w3v[w * 2 + 1];
            p0 = fmaf(fmaxf(bf2f(av0[w] & 0xFFFFu) + bf2f(bv0[w] & 0xFFFFu), 0.f), wa, p0);
            p0 = fmaf(fmaxf(bf2f(av0[w] >> 16)     + bf2f(bv0[w] >> 16),     0.f), wbv, p0);
            p1 = fmaf(fmaxf(bf2f(av1[w] & 0xFFFFu) + bf2f(bv1[w] & 0xFFFFu), 0.f), wa, p1);
            p1 = fmaf(fmaxf(bf2f(av1[w] >> 16)     + bf2f(bv1[w] >> 16),     0.f), wbv, p1);
            p2 = fmaf(fmaxf(bf2f(av2[w] & 0xFFFFu) + bf2f(bv2[w] & 0xFFFFu), 0.f), wa, p2);
            p2 = fmaf(fmaxf(bf2f(av2[w] >> 16)     + bf2f(bv2[w] >> 16),     0.f), wbv, p2);
            p3 = fmaf(fmaxf(bf2f(av3[w] & 0xFFFFu) + bf2f(bv3[w] & 0xFFFFu), 0.f), wa, p3);
            p3 = fmaf(fmaxf(bf2f(av3[w] >> 16)     + bf2f(bv3[w] >> 16),     0.f), wbv, p3);
        }
#pragma unroll
        for (int off = 8; off > 0; off >>= 1) {
            p0 += __shfl_xor(p0, off, 64);
            p1 += __shfl_xor(p1, off, 64);
            p2 += __shfl_xor(p2, off, 64);
            p3 += __shfl_xor(p3, off, 64);
        }
        if (sub == 0) {
            if (v0) out[e0] = 1.f / (1.f + __expf(-(p0 + bb)));
            if (v1) out[e1] = 1.f / (1.f + __expf(-(p1 + bb)));
            if (v2) out[e2] = 1.f / (1.f + __expf(-(p2 + bb)));
            if (v3) out[e3] = 1.f / (1.f + __expf(-(p3 + bb)));
        }
    }
}

// Fallback (only if d_ws too small / nN not multiple of 16): slow, correct.
__global__ __launch_bounds__(256) void fallback_kernel(
    const float* __restrict__ zi, const float* __restrict__ zj,
    const int* __restrict__ src, const int* __restrict__ dst,
    const float* __restrict__ W1, const float* __restrict__ b1,
    const float* __restrict__ W3, const float* __restrict__ b3,
    float* __restrict__ out, int nE)
{
    int e = blockIdx.x * blockDim.x + threadIdx.x;
    if (e >= nE) return;
    const float* a = zi + (size_t)src[e] * DFEAT;
    const float* b = zj + (size_t)dst[e] * DFEAT;
    float logit = b3[0];
    for (int h = 0; h < 128; ++h) {
        float acc = b1[h];
        for (int k = 0; k < 128; ++k) acc = fmaf(a[k], W1[(size_t)k * 128 + h], acc);
        for (int k = 0; k < 128; ++k) acc = fmaf(b[k], W1[(size_t)(128 + k) * 128 + h], acc);
        if (acc > 0.f) logit = fmaf(acc, W3[h], logit);
    }
    out[e] = 1.f / (1.f + __expf(-logit));
}

extern "C" void kernel_launch(void* const* d_in, const int* in_sizes, int n_in,
                              void* d_out, int out_size, void* d_ws, size_t ws_size,
                              hipStream_t stream) {
    const float* zi = (const float*)d_in[0];
    const float* zj = (const float*)d_in[1];
    const int*  src = (const int*)d_in[2];
    const int*  dst = (const int*)d_in[3];
    const float* W1 = (const float*)d_in[4];
    const float* b1 = (const float*)d_in[5];
    const float* W3 = (const float*)d_in[6];
    const float* b3 = (const float*)d_in[7];
    float* out = (float*)d_out;

    int nN = in_sizes[0] / DFEAT;
    int nE = in_sizes[2];
    size_t abytes = (size_t)nN * DFEAT * sizeof(unsigned short);

    if (ws_size >= 2 * abytes && (nN & 15) == 0) {
        unsigned short* A = (unsigned short*)d_ws;
        unsigned short* B = A + (size_t)nN * DFEAT;
        // 512x2 = 1024 blocks = 4/CU; block-per-strip, ~12 strips/block
        dim3 g1(512, 2, 1);
        node_gemm<<<g1, 256, 0, stream>>>(zi, zj, W1, b1, A, B, nN);
        edge_kernel<<<2048, 256, 0, stream>>>(A, B, src, dst, W3, b3, out, nE);
    } else {
        fallback_kernel<<<(nE + 255) / 256, 256, 0, stream>>>(
            zi, zj, src, dst, W1, b1, W3, b3, out, nE);
    }
}

// Round 13
// 74.911 us; speedup vs baseline: 1.0143x; 1.0143x over previous
//
#include <hip/hip_runtime.h>
#include <hip/hip_bf16.h>

typedef __attribute__((ext_vector_type(8))) short short8;
typedef __attribute__((ext_vector_type(4))) float f32x4;
typedef __attribute__((ext_vector_type(4))) unsigned int u32x4;
typedef __attribute__((ext_vector_type(2))) unsigned int u32x2;

#define DFEAT 128
#define LDW 136    // W^T row stride (shorts)
#define LDZ 136    // z-tile row stride (shorts): 272B rows -> <=2-way banks on b128

// Raw barrier WITHOUT the compiler's vmcnt(0) drain (__syncthreads would
// force-retire our cross-iteration prefetch — the m97 stall mechanism).
// lgkmcnt(0) makes this thread's ds_write visible; s_barrier orders threads.
#define LGKM_BARRIER() do {                                   \
    asm volatile("s_waitcnt lgkmcnt(0)" ::: "memory");        \
    __builtin_amdgcn_sched_barrier(0);                        \
    __builtin_amdgcn_s_barrier();                             \
    __builtin_amdgcn_sched_barrier(0);                        \
} while (0)

__device__ __forceinline__ unsigned short f2bf(float f) {
    unsigned int u = __float_as_uint(f);
    u += 0x7FFFu + ((u >> 16) & 1u);   // round-nearest-even
    return (unsigned short)(u >> 16);
}
// packed f32x2 -> bf16x2, RNE (gfx950 v_cvt_pk_bf16_f32)
__device__ __forceinline__ unsigned int cvt2(float lo, float hi) {
    unsigned int r;
    asm("v_cvt_pk_bf16_f32 %0, %1, %2" : "=v"(r) : "v"(lo), "v"(hi));
    return r;
}
__device__ __forceinline__ float bf2f(unsigned int bits) {
    return __uint_as_float(bits << 16);
}

// node_gemm v8 = round-12 v7 with the per-iteration __syncthreads replaced by
// LGKM_BARRIER. That is the ONLY change: __syncthreads emits s_waitcnt
// vmcnt(0) before s_barrier, draining the VMEM queue each iteration and
// killing the 2-deep transit pipeline (rounds 9-12 all pinned at ~46us).
// With the raw barrier, loads issued for strip s+2G stay in flight across
// the barrier and are retired by counted vmcnt one full iteration later.
// In-order VMEM accounting per thread per iter: 2 loads then 2 stores.
//   prologue: A(2)+B(2) -> vmcnt(2) retires A.
//   peeled iter0: after issue A'(2) + stores(2), queue B,A',S -> vmcnt(4)
//     retires B.
//   steady: queue Lprev(2),Sprev(2),Lthis(2),Sthis(2) -> vmcnt(6) retires
//     exactly Lprev.
// Loads always issued (clamped addr) -> uniform counts; stores uniform since
// launcher guards nN % 16 == 0. Loop trip count is block-uniform -> raw
// barrier safe.
__global__ __launch_bounds__(256) void node_gemm(
    const float* __restrict__ zi, const float* __restrict__ zj,
    const float* __restrict__ W1, const float* __restrict__ b1,
    unsigned short* __restrict__ Aout, unsigned short* __restrict__ Bout,
    int nN)
{
    union SMem {
        unsigned short wt[128][LDW];     // 34816 B, W^T staging (prologue only)
        unsigned short zb[2][16][LDZ];   //  8704 B, z double buffer
    };
    __shared__ SMem sm;

    const int table = blockIdx.y;
    const float* __restrict__ z = table ? zj : zi;
    unsigned short* __restrict__ outp = table ? Bout : Aout;
    const int tid = threadIdx.x;

    for (int idx = tid; idx < 128 * 128; idx += 256) {
        int c = idx & 127, k = idx >> 7;
        sm.wt[c][k] = f2bf(W1[(size_t)(table * 128 + k) * DFEAT + c]);
    }
    __syncthreads();   // once: full drain OK

    const int lane = tid & 63;
    const int l15  = lane & 15;
    const int kg   = lane >> 4;
    const int w    = tid >> 6;
    const int cbase = w * 32;

    short8 wf[2][4];
#pragma unroll
    for (int ci = 0; ci < 2; ++ci)
#pragma unroll
        for (int kk = 0; kk < 4; ++kk)
            wf[ci][kk] = *(const short8*)&sm.wt[cbase + ci * 16 + l15][kk * 32 + kg * 8];

    f32x4 biasv[2];
    if (table == 0) {
#pragma unroll
        for (int ci = 0; ci < 2; ++ci)
            biasv[ci] = *(const f32x4*)&b1[cbase + ci * 16 + kg * 4];
    } else {
        biasv[0] = (f32x4){0.f, 0.f, 0.f, 0.f};
        biasv[1] = (f32x4){0.f, 0.f, 0.f, 0.f};
    }
    __syncthreads();   // once: wt reads done; zb may overwrite

    const int nStrips = (nN + 15) >> 4;
    const int G = gridDim.x;
    const int r    = tid >> 4;           // staging row 0..15
    const int coff = (tid & 15) * 8;     // staging col (floats / 8-short units)

    auto gaddr = [&](int s) {
        int row = s * 16 + r;
        if (row >= nN) row = nN - 1;     // clamp: issued loads always legal
        return z + (size_t)row * DFEAT + coff;
    };

    f32x4 t0A, t1A, t0B, t1B;
    auto issueA = [&](int s) {
        const float* gp = gaddr(s);
        asm volatile("global_load_dwordx4 %0, %1, off"           : "=&v"(t0A) : "v"(gp) : "memory");
        asm volatile("global_load_dwordx4 %0, %1, off offset:16" : "=&v"(t1A) : "v"(gp) : "memory");
    };
    auto issueB = [&](int s) {
        const float* gp = gaddr(s);
        asm volatile("global_load_dwordx4 %0, %1, off"           : "=&v"(t0B) : "v"(gp) : "memory");
        asm volatile("global_load_dwordx4 %0, %1, off offset:16" : "=&v"(t1B) : "v"(gp) : "memory");
    };
    auto writeA = [&](int buf) {
        u32x4 v;
        v[0] = cvt2(t0A[0], t0A[1]); v[1] = cvt2(t0A[2], t0A[3]);
        v[2] = cvt2(t1A[0], t1A[1]); v[3] = cvt2(t1A[2], t1A[3]);
        *(u32x4*)&sm.zb[buf][r][coff] = v;
    };
    auto writeB = [&](int buf) {
        u32x4 v;
        v[0] = cvt2(t0B[0], t0B[1]); v[1] = cvt2(t0B[2], t0B[3]);
        v[2] = cvt2(t1B[0], t1B[1]); v[3] = cvt2(t1B[2], t1B[3]);
        *(u32x4*)&sm.zb[buf][r][coff] = v;
    };
    auto compute = [&](int s, int buf) {
        f32x4 acc0 = biasv[0], acc1 = biasv[1];
#pragma unroll
        for (int kk = 0; kk < 4; ++kk) {
            short8 zf = *(const short8*)&sm.zb[buf][l15][kk * 32 + kg * 8];
            acc0 = __builtin_amdgcn_mfma_f32_16x16x32_bf16(wf[0][kk], zf, acc0, 0, 0, 0);
            acc1 = __builtin_amdgcn_mfma_f32_16x16x32_bf16(wf[1][kk], zf, acc1, 0, 0, 0);
        }
        int row = s * 16 + l15;
        if (row < nN) {
            unsigned short* op = outp + (size_t)row * DFEAT + cbase + kg * 4;
            u32x2 v0; v0[0] = cvt2(acc0[0], acc0[1]); v0[1] = cvt2(acc0[2], acc0[3]);
            *(u32x2*)op = v0;
            u32x2 v1; v1[0] = cvt2(acc1[0], acc1[1]); v1[1] = cvt2(acc1[2], acc1[3]);
            *(u32x2*)(op + 16) = v1;
        }
    };

    int s = blockIdx.x;
    // prologue: A <- strip s, B <- strip s+G
    issueA(s);
    issueB(s + G);
    asm volatile("s_waitcnt vmcnt(2)" ::: "memory");   // retire A (B stays in flight)
    __builtin_amdgcn_sched_barrier(0);
    writeA(0);
    LGKM_BARRIER();

    if (s < nStrips) {
        // peeled iter0: compute s (buf0); A free -> issue s+2G
        issueA(s + 2 * G);
        compute(s, 0);
        asm volatile("s_waitcnt vmcnt(4)" ::: "memory");   // retire B
        __builtin_amdgcn_sched_barrier(0);
        writeB(1);
        LGKM_BARRIER();

        int sc = s + G;
        while (sc < nStrips) {
            // odd iter: compute sc (buf1); B free -> issue sc+2G; wait A
            issueB(sc + 2 * G);
            compute(sc, 1);
            asm volatile("s_waitcnt vmcnt(6)" ::: "memory");
            __builtin_amdgcn_sched_barrier(0);
            writeA(0);
            LGKM_BARRIER();
            sc += G;
            if (sc >= nStrips) break;
            // even iter: compute sc (buf0); A free -> issue sc+2G; wait B
            issueA(sc + 2 * G);
            compute(sc, 0);
            asm volatile("s_waitcnt vmcnt(6)" ::: "memory");
            __builtin_amdgcn_sched_barrier(0);
            writeB(1);
            LGKM_BARRIER();
            sc += G;
        }
    }
}

// Phase 2 (round-12, at gather roofline ~45.5us): 16 lanes/edge,
// 4 quads = 16 edges/wave/iter.
__global__ __launch_bounds__(256) void edge_kernel(
    const unsigned short* __restrict__ A, const unsigned short* __restrict__ B,
    const int* __restrict__ src, const int* __restrict__ dst,
    const float* __restrict__ W3, const float* __restrict__ b3,
    float* __restrict__ out, int nE)
{
    const int lane = threadIdx.x & 63;
    const int sub  = lane & 15;
    const int grp  = lane >> 4;

    float w3v[8];
#pragma unroll
    for (int j = 0; j < 8; ++j) w3v[j] = W3[sub * 8 + j];
    const float bb = b3[0];

    int wv = blockIdx.x * 4 + (threadIdx.x >> 6);
    int nw = gridDim.x * 4;

    for (int base = wv * 16; base < nE; base += nw * 16) {
        int e0 = base + grp;
        int e1 = base + 4 + grp;
        int e2 = base + 8 + grp;
        int e3 = base + 12 + grp;
        bool v0 = e0 < nE, v1 = e1 < nE, v2 = e2 < nE, v3 = e3 < nE;
        int s0 = v0 ? src[e0] : 0, d0 = v0 ? dst[e0] : 0;
        int s1 = v1 ? src[e1] : 0, d1 = v1 ? dst[e1] : 0;
        int s2 = v2 ? src[e2] : 0, d2 = v2 ? dst[e2] : 0;
        int s3 = v3 ? src[e3] : 0, d3 = v3 ? dst[e3] : 0;

        u32x4 av0 = *(const u32x4*)(A + (size_t)s0 * DFEAT + sub * 8);
        u32x4 bv0 = *(const u32x4*)(B + (size_t)d0 * DFEAT + sub * 8);
        u32x4 av1 = *(const u32x4*)(A + (size_t)s1 * DFEAT + sub * 8);
        u32x4 bv1 = *(const u32x4*)(B + (size_t)d1 * DFEAT + sub * 8);
        u32x4 av2 = *(const u32x4*)(A + (size_t)s2 * DFEAT + sub * 8);
        u32x4 bv2 = *(const u32x4*)(B + (size_t)d2 * DFEAT + sub * 8);
        u32x4 av3 = *(const u32x4*)(A + (size_t)s3 * DFEAT + sub * 8);
        u32x4 bv3 = *(const u32x4*)(B + (size_t)d3 * DFEAT + sub * 8);

        float p0 = 0.f, p1 = 0.f, p2 = 0.f, p3 = 0.f;
#pragma unroll
        for (int w = 0; w < 4; ++w) {
            float wa = w3v[w * 2], wbv = w3v[w * 2 + 1];
            p0 = fmaf(fmaxf(bf2f(av0[w] & 0xFFFFu) + bf2f(bv0[w] & 0xFFFFu), 0.f), wa, p0);
            p0 = fmaf(fmaxf(bf2f(av0[w] >> 16)     + bf2f(bv0[w] >> 16),     0.f), wbv, p0);
            p1 = fmaf(fmaxf(bf2f(av1[w] & 0xFFFFu) + bf2f(bv1[w] & 0xFFFFu), 0.f), wa, p1);
            p1 = fmaf(fmaxf(bf2f(av1[w] >> 16)     + bf2f(bv1[w] >> 16),     0.f), wbv, p1);
            p2 = fmaf(fmaxf(bf2f(av2[w] & 0xFFFFu) + bf2f(bv2[w] & 0xFFFFu), 0.f), wa, p2);
            p2 = fmaf(fmaxf(bf2f(av2[w] >> 16)     + bf2f(bv2[w] >> 16),     0.f), wbv, p2);
            p3 = fmaf(fmaxf(bf2f(av3[w] & 0xFFFFu) + bf2f(bv3[w] & 0xFFFFu), 0.f), wa, p3);
            p3 = fmaf(fmaxf(bf2f(av3[w] >> 16)     + bf2f(bv3[w] >> 16),     0.f), wbv, p3);
        }
#pragma unroll
        for (int off = 8; off > 0; off >>= 1) {
            p0 += __shfl_xor(p0, off, 64);
            p1 += __shfl_xor(p1, off, 64);
            p2 += __shfl_xor(p2, off, 64);
            p3 += __shfl_xor(p3, off, 64);
        }
        if (sub == 0) {
            if (v0) out[e0] = 1.f / (1.f + __expf(-(p0 + bb)));
            if (v1) out[e1] = 1.f / (1.f + __expf(-(p1 + bb)));
            if (v2) out[e2] = 1.f / (1.f + __expf(-(p2 + bb)));
            if (v3) out[e3] = 1.f / (1.f + __expf(-(p3 + bb)));
        }
    }
}

// Fallback (only if d_ws too small / nN not multiple of 16): slow, correct.
__global__ __launch_bounds__(256) void fallback_kernel(
    const float* __restrict__ zi, const float* __restrict__ zj,
    const int* __restrict__ src, const int* __restrict__ dst,
    const float* __restrict__ W1, const float* __restrict__ b1,
    const float* __restrict__ W3, const float* __restrict__ b3,
    float* __restrict__ out, int nE)
{
    int e = blockIdx.x * blockDim.x + threadIdx.x;
    if (e >= nE) return;
    const float* a = zi + (size_t)src[e] * DFEAT;
    const float* b = zj + (size_t)dst[e] * DFEAT;
    float logit = b3[0];
    for (int h = 0; h < 128; ++h) {
        float acc = b1[h];
        for (int k = 0; k < 128; ++k) acc = fmaf(a[k], W1[(size_t)k * 128 + h], acc);
        for (int k = 0; k < 128; ++k) acc = fmaf(b[k], W1[(size_t)(128 + k) * 128 + h], acc);
        if (acc > 0.f) logit = fmaf(acc, W3[h], logit);
    }
    out[e] = 1.f / (1.f + __expf(-logit));
}

extern "C" void kernel_launch(void* const* d_in, const int* in_sizes, int n_in,
                              void* d_out, int out_size, void* d_ws, size_t ws_size,
                              hipStream_t stream) {
    const float* zi = (const float*)d_in[0];
    const float* zj = (const float*)d_in[1];
    const int*  src = (const int*)d_in[2];
    const int*  dst = (const int*)d_in[3];
    const float* W1 = (const float*)d_in[4];
    const float* b1 = (const float*)d_in[5];
    const float* W3 = (const float*)d_in[6];
    const float* b3 = (const float*)d_in[7];
    float* out = (float*)d_out;

    int nN = in_sizes[0] / DFEAT;
    int nE = in_sizes[2];
    size_t abytes = (size_t)nN * DFEAT * sizeof(unsigned short);

    if (ws_size >= 2 * abytes && (nN & 15) == 0) {
        unsigned short* A = (unsigned short*)d_ws;
        unsigned short* B = A + (size_t)nN * DFEAT;
        // 512x2 = 1024 blocks = 4/CU; block-per-strip, ~12 strips/block
        dim3 g1(512, 2, 1);
        node_gemm<<<g1, 256, 0, stream>>>(zi, zj, W1, b1, A, B, nN);
        edge_kernel<<<2048, 256, 0, stream>>>(A, B, src, dst, W3, b3, out, nE);
    } else {
        fallback_kernel<<<(nE + 255) / 256, 256, 0, stream>>>(
            zi, zj, src, dst, W1, b1, W3, b3, out, nE);
    }
}